// Round 10
// baseline (117.867 us; speedup 1.0000x reference)
//
#include <hip/hip_runtime.h>
#include <math.h>

#define BN 4096
#define FD 512
#define TT 128            // i-tile (rows per block)
#define TJ 64             // j-subtile (cols per block)
#define BK 64             // k-chunk (elements)
#define NJT (BN / TT)     // 32 tiles per dim
#define NPAIR (NJT * (NJT + 1) / 2)   // 528 triangular pairs
#define NBLK (NPAIR * 2)              // 1056 blocks (j split in halves)
#define NPC 128           // partial slots per row: col 0..63, row 64..127

typedef __attribute__((ext_vector_type(8))) __bf16 bf16x8;
typedef __attribute__((ext_vector_type(4))) float floatx4;
typedef unsigned long long u64;

__device__ __forceinline__ float wred_sum(float v) {
#pragma unroll
  for (int m = 1; m < 64; m <<= 1) v += __shfl_xor(v, m, 64);
  return v;
}

__device__ __forceinline__ float dot4(float4 a, float4 b) {
  return a.x * b.x + a.y * b.y + a.z * b.z + a.w * b.w;
}

// round-to-nearest-even f32 -> bf16
__device__ __forceinline__ unsigned short f2bf(float x) {
  unsigned u = __float_as_uint(x);
  u += 0x7fffu + ((u >> 16) & 1u);
  return (unsigned short)(u >> 16);
}

__device__ __forceinline__ void load16(const void* g, void* l) {
  __builtin_amdgcn_global_load_lds(
      (const __attribute__((address_space(1))) unsigned int*)g,
      (__attribute__((address_space(3))) unsigned int*)l, 16, 0, 0);
}

// order-preserving float->uint map (monotone for all finite floats)
__device__ __forceinline__ unsigned ford(float v) {
  unsigned u = __float_as_uint(v);
  return u ^ (((unsigned)((int)u >> 31)) | 0x80000000u);
}

// DPP row-rotate (within 16-lane row) — VALU-pipe cross-lane.
template <int N>
__device__ __forceinline__ int rori(int x) {
  return __builtin_amdgcn_update_dpp(0, x, 0x120 | N, 0xf, 0xf, true);
}
template <int N>
__device__ __forceinline__ u64 ror16_u64(u64 k) {
  unsigned lo = (unsigned)rori<N>((int)(unsigned)k);
  unsigned hi = (unsigned)rori<N>((int)(unsigned)(k >> 32));
  return ((u64)hi << 32) | lo;
}
__device__ __forceinline__ u64 red16_max_u64(u64 k) {
  u64 o;
  o = ror16_u64<1>(k); k = o > k ? o : k;
  o = ror16_u64<2>(k); k = o > k ? o : k;
  o = ror16_u64<4>(k); k = o > k ? o : k;
  o = ror16_u64<8>(k); k = o > k ? o : k;
  return k;
}

// 64-lane xor-shuffle on u64 (two 32-bit shuffles)
__device__ __forceinline__ u64 sx64(u64 v, int m) {
  unsigned lo = (unsigned)__shfl_xor((int)(unsigned)v, m, 64);
  unsigned hi = (unsigned)__shfl_xor((int)(unsigned)(v >> 32), m, 64);
  return ((u64)hi << 32) | lo;
}

// ------- Kernel 1: normalize rows -> bf16 g, recon cosine, SoA angles -------
__global__ __launch_bounds__(256) void k_prep(const float* __restrict__ f,
                                              const float* __restrict__ fo,
                                              const float* __restrict__ angles,
                                              unsigned short* __restrict__ gb,
                                              float* __restrict__ rowr,
                                              float* __restrict__ ax,
                                              float* __restrict__ ay,
                                              float* __restrict__ az) {
  const int i = blockIdx.x * 4 + (threadIdx.x >> 6);
  const int lane = threadIdx.x & 63;
  const int t = blockIdx.x * 256 + threadIdx.x;
  if (t < BN) {
    ax[t] = angles[t * 3 + 0];
    ay[t] = angles[t * 3 + 1];
    az[t] = angles[t * 3 + 2];
  }
  const float4* fr = (const float4*)(f + (size_t)i * FD);
  const float4* orr = (const float4*)(fo + (size_t)i * FD);
  float4 x0 = fr[lane], x1 = fr[lane + 64];
  float4 y0 = orr[lane], y1 = orr[lane + 64];
  float sff = dot4(x0, x0) + dot4(x1, x1);
  float sfo = dot4(x0, y0) + dot4(x1, y1);
  float soo = dot4(y0, y0) + dot4(y1, y1);
  sff = wred_sum(sff);
  sfo = wred_sum(sfo);
  soo = wred_sum(soo);
  float nf = sqrtf(sff);
  float inv = 1.0f / nf;
  ushort4* gr = (ushort4*)(gb + (size_t)i * FD);
  ushort4 s0, s1;
  s0.x = f2bf(x0.x * inv); s0.y = f2bf(x0.y * inv);
  s0.z = f2bf(x0.z * inv); s0.w = f2bf(x0.w * inv);
  s1.x = f2bf(x1.x * inv); s1.y = f2bf(x1.y * inv);
  s1.z = f2bf(x1.z * inv); s1.w = f2bf(x1.w * inv);
  gr[lane] = s0;
  gr[lane + 64] = s1;
  if (lane == 0) {
    rowr[i] = sfo / fmaxf(nf * sqrtf(soo), 1e-8f);
  }
}

// ------- Kernel 2: symmetric bf16 MFMA g.gT, triangular pairs split in j -------
// A-fragments are wave-private -> loaded DIRECTLY global->VGPR (L2-hot);
// only the shared 64-row B-tile goes through LDS (8 KB, swizzled).
// Row-argmax -> slot 64+2b+h; per-wave col-argmax -> slot 4a+w (skip if a==b).
__global__ __launch_bounds__(256) void k_sim(const unsigned short* __restrict__ gb,
                                             const int* __restrict__ labels,
                                             const float* __restrict__ ax,
                                             const float* __restrict__ ay,
                                             const float* __restrict__ az,
                                             u64* __restrict__ pkey) {
  __shared__ unsigned short Bs[TJ * BK];   // 8 KB
  const int h = blockIdx.x & 1;
  int a = 0, rem = blockIdx.x >> 1;
#pragma unroll 1
  while (rem >= NJT - a) { rem -= NJT - a; a++; }
  const int b = a + rem;
  const int i0 = a * TT;
  const int j0 = b * TT + h * TJ;

  const int tid = threadIdx.x;
  const int w = tid >> 6;
  const int lane = tid & 63;

  floatx4 acc[2][4];
#pragma unroll
  for (int u = 0; u < 2; u++)
#pragma unroll
    for (int v = 0; v < 4; v++) acc[u][v] = (floatx4){0.f, 0.f, 0.f, 0.f};

  // B staging: position p = tid + 256c holds row p>>3, logical chunk (p&7)^((p>>3)&7).
  const int rp = tid >> 3;                          // 0..31
  const int q8 = ((tid & 7) ^ (rp & 7)) * 8;        // global chunk offset (elems)
  const unsigned short* gB[2];
  unsigned short* lB[2];
#pragma unroll
  for (int c = 0; c < 2; c++) {
    gB[c] = gb + (size_t)(j0 + rp + 32 * c) * FD + q8;
    lB[c] = Bs + (tid + 256 * c) * 8;
  }

  // Fragment addressing.
  const int m = lane & 15;
  const int g4 = lane >> 4;
  const int l7 = lane & 7;
  const int koff0 = (g4 ^ l7) * 8;      // LDS swizzled chunk, k-half 0
  const int koff1 = ((4 + g4) ^ l7) * 8;
  const int brow = m;
  // A direct-from-global: row i0 + w*32 + m (+u*16), k = kc + h2*32 + g4*8
  const unsigned short* gA0 = gb + (size_t)(i0 + w * 32 + m) * FD + g4 * 8;

  for (int kc = 0; kc < FD; kc += BK) {
    load16(gB[0] + kc, lB[0]);
    load16(gB[1] + kc, lB[1]);
    bf16x8 af0[2], af1[2];
#pragma unroll
    for (int u = 0; u < 2; u++) {
      af0[u] = *(const bf16x8*)(gA0 + (size_t)u * 16 * FD + kc);
      af1[u] = *(const bf16x8*)(gA0 + (size_t)u * 16 * FD + kc + 32);
    }
    __syncthreads();
    bf16x8 bf[4];
#pragma unroll
    for (int v = 0; v < 4; v++)
      bf[v] = *(const bf16x8*)(Bs + (brow + v * 16) * BK + koff0);
#pragma unroll
    for (int u = 0; u < 2; u++)
#pragma unroll
      for (int v = 0; v < 4; v++)
        acc[u][v] = __builtin_amdgcn_mfma_f32_16x16x32_bf16(af0[u], bf[v], acc[u][v], 0, 0, 0);
#pragma unroll
    for (int v = 0; v < 4; v++)
      bf[v] = *(const bf16x8*)(Bs + (brow + v * 16) * BK + koff1);
#pragma unroll
    for (int u = 0; u < 2; u++)
#pragma unroll
      for (int v = 0; v < 4; v++)
        acc[u][v] = __builtin_amdgcn_mfma_f32_16x16x32_bf16(af1[u], bf[v], acc[u][v], 0, 0, 0);
    __syncthreads();
  }

  // Epilogue: C layout col=lane&15, row=quad*4+reg (16x16 family).
  const int quad = lane >> 4;
  const int cx = lane & 15;
  int jc[4], lj[4];
  float jx[4], jy[4], jz[4];
#pragma unroll
  for (int v = 0; v < 4; v++) {
    jc[v] = j0 + v * 16 + cx;
    lj[v] = labels[jc[v]];
    jx[v] = ax[jc[v]];
    jy[v] = ay[jc[v]];
    jz[v] = az[jc[v]];
  }
  const size_t rbase = (size_t)(64 + 2 * b + h) * BN;   // row-part slot
  u64 ckey[4] = {0, 0, 0, 0};                           // col-part keys per v
#pragma unroll
  for (int u = 0; u < 2; u++) {
#pragma unroll
    for (int reg = 0; reg < 4; reg++) {
      int i = i0 + w * 32 + u * 16 + quad * 4 + reg;
      int li = labels[i];
      float a0 = ax[i], a1 = ay[i], a2 = az[i];
      u64 rkey = 0;
      unsigned ni = (unsigned)(~i);
#pragma unroll
      for (int v = 0; v < 4; v++) {
        float d0 = a0 - jx[v];
        float d1 = a1 - jy[v];
        float d2 = a2 - jz[v];
        float dd = d0 * d0 + d1 * d1 + d2 * d2;
        bool ok = (li != lj[v]) && (dd < 900.0f);   // sqrt(dd)<30
        u64 vh = (u64)ford(acc[u][v][reg]) << 32;
        u64 candR = vh | (unsigned)(~jc[v]);
        if (ok && candR > rkey) rkey = candR;
        u64 candC = vh | ni;
        if (ok && candC > ckey[v]) ckey[v] = candC;
      }
      rkey = red16_max_u64(rkey);
      if (cx == 0) pkey[rbase + i] = rkey;
    }
  }
  if (a != b) {
    // per-wave column argmax over this wave's 32 rows: reduce across quads
    const size_t cbase = (size_t)(4 * a + w) * BN;
#pragma unroll
    for (int v = 0; v < 4; v++) {
      u64 k = ckey[v];
      u64 o = sx64(k, 16); if (o > k) k = o;
      o = sx64(k, 32); if (o > k) k = o;
      if (quad == 0) pkey[cbase + jc[v]] = k;
    }
  }
}

// ------- Kernel 3: per-row finalize — LDS-tiled angle scan + masked S merge -------
// Valid S slots for row i (tile t=i>>7): col slots [0,4t), row slots [64+2t,128).
__global__ __launch_bounds__(256) void k_final(const float* __restrict__ f,
                                               const int* __restrict__ labels,
                                               const float* __restrict__ ax,
                                               const float* __restrict__ ay,
                                               const float* __restrict__ az,
                                               const u64* __restrict__ pkey,
                                               float* __restrict__ rowc,
                                               float* __restrict__ rowv) {
  __shared__ float4 sax[256], say[256], saz[256];
  __shared__ int4 slb[256];
  const int i = blockIdx.x * 4 + (threadIdx.x >> 6);
  const int lane = threadIdx.x & 63;
  const int tid = threadIdx.x;
  const int li = labels[i];
  const float a0 = ax[i], a1 = ay[i], a2 = az[i];

  // P: max dd among same-label j!=i -> max key (dd<<32 | ~j), tie->smaller j.
  // N: min dd among diff-label      -> min key (dd<<32 |  j), tie->smaller j.
  u64 keyP = 0;
  u64 keyN = ~0ull;
  const float4* ax4 = (const float4*)ax;
  const float4* ay4 = (const float4*)ay;
  const float4* az4 = (const float4*)az;
  const int4* lb4 = (const int4*)labels;
#pragma unroll 1
  for (int r = 0; r < 4; r++) {
    sax[tid] = ax4[r * 256 + tid];
    say[tid] = ay4[r * 256 + tid];
    saz[tid] = az4[r * 256 + tid];
    slb[tid] = lb4[r * 256 + tid];
    __syncthreads();
#pragma unroll
    for (int it = 0; it < 4; it++) {
      int idx = it * 64 + lane;
      float4 X = sax[idx], Y = say[idx], Z = saz[idx];
      int4 L = slb[idx];
      int jb = (r * 256 + idx) * 4;
#pragma unroll
      for (int s = 0; s < 4; s++) {
        float xx = s == 0 ? X.x : s == 1 ? X.y : s == 2 ? X.z : X.w;
        float yy = s == 0 ? Y.x : s == 1 ? Y.y : s == 2 ? Y.z : Y.w;
        float zz = s == 0 ? Z.x : s == 1 ? Z.y : s == 2 ? Z.z : Z.w;
        int ll = s == 0 ? L.x : s == 1 ? L.y : s == 2 ? L.z : L.w;
        int j = jb + s;
        float d0 = a0 - xx, d1 = a1 - yy, d2 = a2 - zz;
        float dd = d0 * d0 + d1 * d1 + d2 * d2;
        if (ll == li) {
          u64 kp = ((u64)__float_as_uint(dd) << 32) | (unsigned)(~j);
          if (j != i && kp > keyP) keyP = kp;
        } else {
          u64 kn = ((u64)__float_as_uint(dd) << 32) | (unsigned)j;
          if (kn < keyN) keyN = kn;
        }
      }
    }
    __syncthreads();
  }
  // S partials: two slots per lane with stale-slot masks
  const int t = i >> 7;
  u64 s0 = (lane < 4 * t) ? pkey[(size_t)lane * BN + i] : 0;
  u64 s1 = (lane >= 2 * t) ? pkey[(size_t)(64 + lane) * BN + i] : 0;
  u64 keyS = s0 > s1 ? s0 : s1;
#pragma unroll
  for (int off = 1; off < 64; off <<= 1) {
    u64 o = sx64(keyP, off);
    if (o > keyP) keyP = o;
    o = sx64(keyN, off);
    if (o < keyN) keyN = o;
    o = sx64(keyS, off);
    if (o > keyS) keyS = o;
  }
  bool hp = keyP != 0;
  bool hn = keyN != ~0ull;
  if (!(hp && hn)) {
    if (lane == 0) { rowc[i] = 0.0f; rowv[i] = 0.0f; }
    return;
  }
  bool sim_any = keyS != 0;
  int pos = (int)(~(unsigned)keyP);
  int neg = sim_any ? (int)(~(unsigned)keyS) : (int)(unsigned)keyN;

  // triplet distances (reference adds 1e-6 to the per-element difference)
  const float4* fa = (const float4*)(f + (size_t)i * FD);
  const float4* fp = (const float4*)(f + (size_t)pos * FD);
  const float4* fn = (const float4*)(f + (size_t)neg * FD);
  float sp = 0.0f, sn = 0.0f;
#pragma unroll
  for (int t2 = 0; t2 < 2; t2++) {
    float4 xa = fa[lane + t2 * 64];
    float4 xp = fp[lane + t2 * 64];
    float4 xn = fn[lane + t2 * 64];
    float dp;
    dp = xa.x - xp.x + 1e-6f; sp += dp * dp;
    dp = xa.y - xp.y + 1e-6f; sp += dp * dp;
    dp = xa.z - xp.z + 1e-6f; sp += dp * dp;
    dp = xa.w - xp.w + 1e-6f; sp += dp * dp;
    dp = xa.x - xn.x + 1e-6f; sn += dp * dp;
    dp = xa.y - xn.y + 1e-6f; sn += dp * dp;
    dp = xa.z - xn.z + 1e-6f; sn += dp * dp;
    dp = xa.w - xn.w + 1e-6f; sn += dp * dp;
  }
  sp = wred_sum(sp);
  sn = wred_sum(sn);

  if (lane == 0) {
    float pos_d = sqrtf(sp);
    float neg_d = sqrtf(sn);
    float pa = sqrtf(__uint_as_float((unsigned)(keyP >> 32)));
    float n0 = a0 - ax[neg];
    float n1 = a1 - ay[neg];
    float n2 = a2 - az[neg];
    float na = sqrtf(n0 * n0 + n1 * n1 + n2 * n2);
    float w = (pa > 45.0f ? 2.0f : 1.0f) * (na < 15.0f ? 1.5f : 1.0f);
    float basic = fmaxf(pos_d - neg_d + 0.2f, 0.0f);
    rowc[i] = w * basic;
    rowv[i] = 1.0f;
  }
}

// ------- Kernel 4: single-block tree reduction + scalar assembly -------
__global__ __launch_bounds__(1024) void k_out(const float* __restrict__ rowc,
                                              const float* __restrict__ rowv,
                                              const float* __restrict__ rowr,
                                              float* __restrict__ out) {
  __shared__ float sc[16], sv[16], sr[16];
  const int t = threadIdx.x;
  float c = 0.0f, v = 0.0f, r = 0.0f;
  for (int i = t; i < BN; i += 1024) {
    c += rowc[i];
    v += rowv[i];
    r += rowr[i];
  }
  c = wred_sum(c);
  v = wred_sum(v);
  r = wred_sum(r);
  const int wid = t >> 6;
  if ((t & 63) == 0) { sc[wid] = c; sv[wid] = v; sr[wid] = r; }
  __syncthreads();
  if (t == 0) {
    float C = 0.0f, V = 0.0f, R = 0.0f;
#pragma unroll
    for (int k = 0; k < 16; k++) { C += sc[k]; V += sv[k]; R += sr[k]; }
    float tri = C / fmaxf(V, 1.0f);
    float recon = 1.0f - R / (float)BN;
    out[0] = tri + 0.1f * recon;
  }
}

extern "C" void kernel_launch(void* const* d_in, const int* in_sizes, int n_in,
                              void* d_out, int out_size, void* d_ws, size_t ws_size,
                              hipStream_t stream) {
  const float* feat = (const float*)d_in[0];
  const int* labels = (const int*)d_in[1];
  const float* angles = (const float*)d_in[2];
  const float* forig = (const float*)d_in[3];
  float* out = (float*)d_out;

  char* ws = (char*)d_ws;
  unsigned short* gb = (unsigned short*)ws;                    // 4 MB bf16 normalized rows
  size_t off = (size_t)BN * FD * sizeof(unsigned short);
  u64* pkey = (u64*)(ws + off);     off += (size_t)NPC * BN * 8;   // 4 MB
  float* rowc = (float*)(ws + off); off += (size_t)BN * 4;
  float* rowv = (float*)(ws + off); off += (size_t)BN * 4;
  float* rowr = (float*)(ws + off); off += (size_t)BN * 4;
  float* ax = (float*)(ws + off);   off += (size_t)BN * 4;
  float* ay = (float*)(ws + off);   off += (size_t)BN * 4;
  float* az = (float*)(ws + off);   off += (size_t)BN * 4;

  k_prep<<<BN / 4, 256, 0, stream>>>(feat, forig, angles, gb, rowr, ax, ay, az);
  k_sim<<<NBLK, 256, 0, stream>>>(gb, labels, ax, ay, az, pkey);
  k_final<<<BN / 4, 256, 0, stream>>>(feat, labels, ax, ay, az, pkey, rowc, rowv);
  k_out<<<1, 1024, 0, stream>>>(rowc, rowv, rowr, out);
}

// Round 11
// 108.397 us; speedup vs baseline: 1.0874x; 1.0874x over previous
//
#include <hip/hip_runtime.h>
#include <math.h>

#define BN 4096
#define FD 512
#define TT 128            // i-tile (rows per block)
#define TJ 64             // j-subtile (cols per block)
#define BK 64             // k-chunk (elements)
#define NJT (BN / TT)     // 32 tiles per dim
#define NPAIR (NJT * (NJT + 1) / 2)   // 528 triangular pairs
#define NBLK (NPAIR * 2)              // 1056 blocks (j split in halves)
#define NPC 128           // partial slots per row: col 0..63, row 64..127

typedef __attribute__((ext_vector_type(8))) __bf16 bf16x8;
typedef __attribute__((ext_vector_type(4))) float floatx4;
typedef unsigned long long u64;

__device__ __forceinline__ float wred_sum(float v) {
#pragma unroll
  for (int m = 1; m < 64; m <<= 1) v += __shfl_xor(v, m, 64);
  return v;
}

__device__ __forceinline__ float dot4(float4 a, float4 b) {
  return a.x * b.x + a.y * b.y + a.z * b.z + a.w * b.w;
}

// round-to-nearest-even f32 -> bf16
__device__ __forceinline__ unsigned short f2bf(float x) {
  unsigned u = __float_as_uint(x);
  u += 0x7fffu + ((u >> 16) & 1u);
  return (unsigned short)(u >> 16);
}

__device__ __forceinline__ void load16(const void* g, void* l) {
  __builtin_amdgcn_global_load_lds(
      (const __attribute__((address_space(1))) unsigned int*)g,
      (__attribute__((address_space(3))) unsigned int*)l, 16, 0, 0);
}

// order-preserving float->uint map (monotone for all finite floats)
__device__ __forceinline__ unsigned ford(float v) {
  unsigned u = __float_as_uint(v);
  return u ^ (((unsigned)((int)u >> 31)) | 0x80000000u);
}

// DPP row-rotate (within 16-lane row) — VALU-pipe cross-lane.
template <int N>
__device__ __forceinline__ int rori(int x) {
  return __builtin_amdgcn_update_dpp(0, x, 0x120 | N, 0xf, 0xf, true);
}
template <int N>
__device__ __forceinline__ u64 ror16_u64(u64 k) {
  unsigned lo = (unsigned)rori<N>((int)(unsigned)k);
  unsigned hi = (unsigned)rori<N>((int)(unsigned)(k >> 32));
  return ((u64)hi << 32) | lo;
}
__device__ __forceinline__ u64 red16_max_u64(u64 k) {
  u64 o;
  o = ror16_u64<1>(k); k = o > k ? o : k;
  o = ror16_u64<2>(k); k = o > k ? o : k;
  o = ror16_u64<4>(k); k = o > k ? o : k;
  o = ror16_u64<8>(k); k = o > k ? o : k;
  return k;
}

// 64-lane xor-shuffle on u64 (two 32-bit shuffles)
__device__ __forceinline__ u64 sx64(u64 v, int m) {
  unsigned lo = (unsigned)__shfl_xor((int)(unsigned)v, m, 64);
  unsigned hi = (unsigned)__shfl_xor((int)(unsigned)(v >> 32), m, 64);
  return ((u64)hi << 32) | lo;
}

// ------- Kernel 1: normalize rows -> bf16 g, recon cosine, SoA angles -------
__global__ __launch_bounds__(256) void k_prep(const float* __restrict__ f,
                                              const float* __restrict__ fo,
                                              const float* __restrict__ angles,
                                              unsigned short* __restrict__ gb,
                                              float* __restrict__ rowr,
                                              float* __restrict__ ax,
                                              float* __restrict__ ay,
                                              float* __restrict__ az) {
  const int i = blockIdx.x * 4 + (threadIdx.x >> 6);
  const int lane = threadIdx.x & 63;
  const int t = blockIdx.x * 256 + threadIdx.x;
  if (t < BN) {
    ax[t] = angles[t * 3 + 0];
    ay[t] = angles[t * 3 + 1];
    az[t] = angles[t * 3 + 2];
  }
  const float4* fr = (const float4*)(f + (size_t)i * FD);
  const float4* orr = (const float4*)(fo + (size_t)i * FD);
  float4 x0 = fr[lane], x1 = fr[lane + 64];
  float4 y0 = orr[lane], y1 = orr[lane + 64];
  float sff = dot4(x0, x0) + dot4(x1, x1);
  float sfo = dot4(x0, y0) + dot4(x1, y1);
  float soo = dot4(y0, y0) + dot4(y1, y1);
  sff = wred_sum(sff);
  sfo = wred_sum(sfo);
  soo = wred_sum(soo);
  float nf = sqrtf(sff);
  float inv = 1.0f / nf;
  ushort4* gr = (ushort4*)(gb + (size_t)i * FD);
  ushort4 s0, s1;
  s0.x = f2bf(x0.x * inv); s0.y = f2bf(x0.y * inv);
  s0.z = f2bf(x0.z * inv); s0.w = f2bf(x0.w * inv);
  s1.x = f2bf(x1.x * inv); s1.y = f2bf(x1.y * inv);
  s1.z = f2bf(x1.z * inv); s1.w = f2bf(x1.w * inv);
  gr[lane] = s0;
  gr[lane + 64] = s1;
  if (lane == 0) {
    rowr[i] = sfo / fmaxf(nf * sqrtf(soo), 1e-8f);
  }
}

// ------- Kernel 2: symmetric bf16 MFMA g.gT, triangular pairs split in j -------
// Round-9 structure (A+B through swizzled LDS) + __launch_bounds__(256,4):
// VGPR was 132 (3 waves/SIMD); forcing <=128 gives 4 waves/SIMD (+33% TLP).
__global__ __launch_bounds__(256, 4) void k_sim(const unsigned short* __restrict__ gb,
                                                const int* __restrict__ labels,
                                                const float* __restrict__ ax,
                                                const float* __restrict__ ay,
                                                const float* __restrict__ az,
                                                u64* __restrict__ pkey) {
  __shared__ unsigned short As[TT * BK];   // 16 KB
  __shared__ unsigned short Bs[TJ * BK];   // 8 KB
  const int h = blockIdx.x & 1;
  int a = 0, rem = blockIdx.x >> 1;
#pragma unroll 1
  while (rem >= NJT - a) { rem -= NJT - a; a++; }
  const int b = a + rem;
  const int i0 = a * TT;
  const int j0 = b * TT + h * TJ;

  const int tid = threadIdx.x;
  const int w = tid >> 6;
  const int lane = tid & 63;

  floatx4 acc[2][4];
#pragma unroll
  for (int u = 0; u < 2; u++)
#pragma unroll
    for (int v = 0; v < 4; v++) acc[u][v] = (floatx4){0.f, 0.f, 0.f, 0.f};

  // Staging: position p = tid + 256c holds row p>>3, logical chunk (p&7)^((p>>3)&7).
  const int rp = tid >> 3;                          // 0..31
  const int q8 = ((tid & 7) ^ (rp & 7)) * 8;        // global chunk offset (elems)
  const unsigned short* gA[4];
  const unsigned short* gB[2];
  unsigned short* lA[4];
  unsigned short* lB[2];
#pragma unroll
  for (int c = 0; c < 4; c++) {
    gA[c] = gb + (size_t)(i0 + rp + 32 * c) * FD + q8;
    lA[c] = As + (tid + 256 * c) * 8;
  }
#pragma unroll
  for (int c = 0; c < 2; c++) {
    gB[c] = gb + (size_t)(j0 + rp + 32 * c) * FD + q8;
    lB[c] = Bs + (tid + 256 * c) * 8;
  }

  // Fragment reads: swizzled chunk position q ^ (lane&7).
  const int m = lane & 15;
  const int arow = w * 32 + m;      // + u*16
  const int brow = m;               // + v*16
  const int g4 = lane >> 4;
  const int l7 = lane & 7;
  const int koff0 = (g4 ^ l7) * 8;
  const int koff1 = ((4 + g4) ^ l7) * 8;

  for (int kc = 0; kc < FD; kc += BK) {
#pragma unroll
    for (int c = 0; c < 4; c++) load16(gA[c] + kc, lA[c]);
#pragma unroll
    for (int c = 0; c < 2; c++) load16(gB[c] + kc, lB[c]);
    __syncthreads();
    bf16x8 af[2], bf[4];
#pragma unroll
    for (int u = 0; u < 2; u++)
      af[u] = *(const bf16x8*)(As + (arow + u * 16) * BK + koff0);
#pragma unroll
    for (int v = 0; v < 4; v++)
      bf[v] = *(const bf16x8*)(Bs + (brow + v * 16) * BK + koff0);
#pragma unroll
    for (int u = 0; u < 2; u++)
#pragma unroll
      for (int v = 0; v < 4; v++)
        acc[u][v] = __builtin_amdgcn_mfma_f32_16x16x32_bf16(af[u], bf[v], acc[u][v], 0, 0, 0);
#pragma unroll
    for (int u = 0; u < 2; u++)
      af[u] = *(const bf16x8*)(As + (arow + u * 16) * BK + koff1);
#pragma unroll
    for (int v = 0; v < 4; v++)
      bf[v] = *(const bf16x8*)(Bs + (brow + v * 16) * BK + koff1);
#pragma unroll
    for (int u = 0; u < 2; u++)
#pragma unroll
      for (int v = 0; v < 4; v++)
        acc[u][v] = __builtin_amdgcn_mfma_f32_16x16x32_bf16(af[u], bf[v], acc[u][v], 0, 0, 0);
    __syncthreads();
  }

  // Epilogue: C layout col=lane&15, row=quad*4+reg (16x16 family).
  const int quad = lane >> 4;
  const int cx = lane & 15;
  int jc[4], lj[4];
  float jx[4], jy[4], jz[4];
#pragma unroll
  for (int v = 0; v < 4; v++) {
    jc[v] = j0 + v * 16 + cx;
    lj[v] = labels[jc[v]];
    jx[v] = ax[jc[v]];
    jy[v] = ay[jc[v]];
    jz[v] = az[jc[v]];
  }
  const size_t rbase = (size_t)(64 + 2 * b + h) * BN;   // row-part slot
  u64 ckey[4] = {0, 0, 0, 0};                           // col-part keys per v
#pragma unroll
  for (int u = 0; u < 2; u++) {
#pragma unroll
    for (int reg = 0; reg < 4; reg++) {
      int i = i0 + w * 32 + u * 16 + quad * 4 + reg;
      int li = labels[i];
      float a0 = ax[i], a1 = ay[i], a2 = az[i];
      u64 rkey = 0;
      unsigned ni = (unsigned)(~i);
#pragma unroll
      for (int v = 0; v < 4; v++) {
        float d0 = a0 - jx[v];
        float d1 = a1 - jy[v];
        float d2 = a2 - jz[v];
        float dd = d0 * d0 + d1 * d1 + d2 * d2;
        bool ok = (li != lj[v]) && (dd < 900.0f);   // sqrt(dd)<30
        u64 vh = (u64)ford(acc[u][v][reg]) << 32;
        u64 candR = vh | (unsigned)(~jc[v]);
        if (ok && candR > rkey) rkey = candR;
        u64 candC = vh | ni;
        if (ok && candC > ckey[v]) ckey[v] = candC;
      }
      rkey = red16_max_u64(rkey);
      if (cx == 0) pkey[rbase + i] = rkey;
    }
  }
  if (a != b) {
    // per-wave column argmax over this wave's 32 rows: reduce across quads
    const size_t cbase = (size_t)(4 * a + w) * BN;
#pragma unroll
    for (int v = 0; v < 4; v++) {
      u64 k = ckey[v];
      u64 o = sx64(k, 16); if (o > k) k = o;
      o = sx64(k, 32); if (o > k) k = o;
      if (quad == 0) pkey[cbase + jc[v]] = k;
    }
  }
}

// ------- Kernel 3: per-row finalize — SoA angle scan + masked S merge -------
// Valid S slots for row i (tile t=i>>7): col slots [0,4t), row slots [64+2t,128).
__global__ __launch_bounds__(256) void k_final(const float* __restrict__ f,
                                               const int* __restrict__ labels,
                                               const float* __restrict__ ax,
                                               const float* __restrict__ ay,
                                               const float* __restrict__ az,
                                               const u64* __restrict__ pkey,
                                               float* __restrict__ rowc,
                                               float* __restrict__ rowv) {
  const int i = blockIdx.x * 4 + (threadIdx.x >> 6);
  const int lane = threadIdx.x & 63;
  const int li = labels[i];
  const float a0 = ax[i], a1 = ay[i], a2 = az[i];

  // P: max dd among same-label j!=i -> max key (dd<<32 | ~j), tie->smaller j.
  // N: min dd among diff-label      -> min key (dd<<32 |  j), tie->smaller j.
  u64 keyP = 0;
  u64 keyN = ~0ull;
  const float4* ax4 = (const float4*)ax;
  const float4* ay4 = (const float4*)ay;
  const float4* az4 = (const float4*)az;
  const int4* lb4 = (const int4*)labels;
#pragma unroll
  for (int it = 0; it < 16; it++) {
    int bb = it * 64 + lane;           // float4 index; j = 4bb..4bb+3
    float4 X = ax4[bb], Y = ay4[bb], Z = az4[bb];
    int4 L = lb4[bb];
    int jb = bb * 4;
#pragma unroll
    for (int s = 0; s < 4; s++) {
      float xx = s == 0 ? X.x : s == 1 ? X.y : s == 2 ? X.z : X.w;
      float yy = s == 0 ? Y.x : s == 1 ? Y.y : s == 2 ? Y.z : Y.w;
      float zz = s == 0 ? Z.x : s == 1 ? Z.y : s == 2 ? Z.z : Z.w;
      int ll = s == 0 ? L.x : s == 1 ? L.y : s == 2 ? L.z : L.w;
      int j = jb + s;
      float d0 = a0 - xx, d1 = a1 - yy, d2 = a2 - zz;
      float dd = d0 * d0 + d1 * d1 + d2 * d2;
      if (ll == li) {
        u64 kp = ((u64)__float_as_uint(dd) << 32) | (unsigned)(~j);
        if (j != i && kp > keyP) keyP = kp;
      } else {
        u64 kn = ((u64)__float_as_uint(dd) << 32) | (unsigned)j;
        if (kn < keyN) keyN = kn;
      }
    }
  }
  // S partials: two slots per lane with stale-slot masks
  const int t = i >> 7;
  u64 s0 = (lane < 4 * t) ? pkey[(size_t)lane * BN + i] : 0;
  u64 s1 = (lane >= 2 * t) ? pkey[(size_t)(64 + lane) * BN + i] : 0;
  u64 keyS = s0 > s1 ? s0 : s1;
#pragma unroll
  for (int off = 1; off < 64; off <<= 1) {
    u64 o = sx64(keyP, off);
    if (o > keyP) keyP = o;
    o = sx64(keyN, off);
    if (o < keyN) keyN = o;
    o = sx64(keyS, off);
    if (o > keyS) keyS = o;
  }
  bool hp = keyP != 0;
  bool hn = keyN != ~0ull;
  if (!(hp && hn)) {
    if (lane == 0) { rowc[i] = 0.0f; rowv[i] = 0.0f; }
    return;
  }
  bool sim_any = keyS != 0;
  int pos = (int)(~(unsigned)keyP);
  int neg = sim_any ? (int)(~(unsigned)keyS) : (int)(unsigned)keyN;

  // triplet distances (reference adds 1e-6 to the per-element difference)
  const float4* fa = (const float4*)(f + (size_t)i * FD);
  const float4* fp = (const float4*)(f + (size_t)pos * FD);
  const float4* fn = (const float4*)(f + (size_t)neg * FD);
  float sp = 0.0f, sn = 0.0f;
#pragma unroll
  for (int t2 = 0; t2 < 2; t2++) {
    float4 xa = fa[lane + t2 * 64];
    float4 xp = fp[lane + t2 * 64];
    float4 xn = fn[lane + t2 * 64];
    float dp;
    dp = xa.x - xp.x + 1e-6f; sp += dp * dp;
    dp = xa.y - xp.y + 1e-6f; sp += dp * dp;
    dp = xa.z - xp.z + 1e-6f; sp += dp * dp;
    dp = xa.w - xp.w + 1e-6f; sp += dp * dp;
    dp = xa.x - xn.x + 1e-6f; sn += dp * dp;
    dp = xa.y - xn.y + 1e-6f; sn += dp * dp;
    dp = xa.z - xn.z + 1e-6f; sn += dp * dp;
    dp = xa.w - xn.w + 1e-6f; sn += dp * dp;
  }
  sp = wred_sum(sp);
  sn = wred_sum(sn);

  if (lane == 0) {
    float pos_d = sqrtf(sp);
    float neg_d = sqrtf(sn);
    float pa = sqrtf(__uint_as_float((unsigned)(keyP >> 32)));
    float n0 = a0 - ax[neg];
    float n1 = a1 - ay[neg];
    float n2 = a2 - az[neg];
    float na = sqrtf(n0 * n0 + n1 * n1 + n2 * n2);
    float w = (pa > 45.0f ? 2.0f : 1.0f) * (na < 15.0f ? 1.5f : 1.0f);
    float basic = fmaxf(pos_d - neg_d + 0.2f, 0.0f);
    rowc[i] = w * basic;
    rowv[i] = 1.0f;
  }
}

// ------- Kernel 4: single-block tree reduction + scalar assembly -------
__global__ __launch_bounds__(1024) void k_out(const float* __restrict__ rowc,
                                              const float* __restrict__ rowv,
                                              const float* __restrict__ rowr,
                                              float* __restrict__ out) {
  __shared__ float sc[16], sv[16], sr[16];
  const int t = threadIdx.x;
  float c = 0.0f, v = 0.0f, r = 0.0f;
  for (int i = t; i < BN; i += 1024) {
    c += rowc[i];
    v += rowv[i];
    r += rowr[i];
  }
  c = wred_sum(c);
  v = wred_sum(v);
  r = wred_sum(r);
  const int wid = t >> 6;
  if ((t & 63) == 0) { sc[wid] = c; sv[wid] = v; sr[wid] = r; }
  __syncthreads();
  if (t == 0) {
    float C = 0.0f, V = 0.0f, R = 0.0f;
#pragma unroll
    for (int k = 0; k < 16; k++) { C += sc[k]; V += sv[k]; R += sr[k]; }
    float tri = C / fmaxf(V, 1.0f);
    float recon = 1.0f - R / (float)BN;
    out[0] = tri + 0.1f * recon;
  }
}

extern "C" void kernel_launch(void* const* d_in, const int* in_sizes, int n_in,
                              void* d_out, int out_size, void* d_ws, size_t ws_size,
                              hipStream_t stream) {
  const float* feat = (const float*)d_in[0];
  const int* labels = (const int*)d_in[1];
  const float* angles = (const float*)d_in[2];
  const float* forig = (const float*)d_in[3];
  float* out = (float*)d_out;

  char* ws = (char*)d_ws;
  unsigned short* gb = (unsigned short*)ws;                    // 4 MB bf16 normalized rows
  size_t off = (size_t)BN * FD * sizeof(unsigned short);
  u64* pkey = (u64*)(ws + off);     off += (size_t)NPC * BN * 8;   // 4 MB
  float* rowc = (float*)(ws + off); off += (size_t)BN * 4;
  float* rowv = (float*)(ws + off); off += (size_t)BN * 4;
  float* rowr = (float*)(ws + off); off += (size_t)BN * 4;
  float* ax = (float*)(ws + off);   off += (size_t)BN * 4;
  float* ay = (float*)(ws + off);   off += (size_t)BN * 4;
  float* az = (float*)(ws + off);   off += (size_t)BN * 4;

  k_prep<<<BN / 4, 256, 0, stream>>>(feat, forig, angles, gb, rowr, ax, ay, az);
  k_sim<<<NBLK, 256, 0, stream>>>(gb, labels, ax, ay, az, pkey);
  k_final<<<BN / 4, 256, 0, stream>>>(feat, labels, ax, ay, az, pkey, rowc, rowv);
  k_out<<<1, 1024, 0, stream>>>(rowc, rowv, rowr, out);
}